// Round 4
// baseline (126.304 us; speedup 1.0000x reference)
//
#include <hip/hip_runtime.h>

#define HH   128
#define WW   128
#define HW   (HH * WW)
#define CC   64
#define TILE 16
#define HALO 20
#define NHP  (HALO * HALO)   // 400 halo pixels = 25 exact 16-px MFMA tiles
#define SWZ(r) (((r) >> 1) & 7)

typedef unsigned int uint32;
typedef _Float16 h2   __attribute__((ext_vector_type(2)));
typedef __fp16   h2b  __attribute__((ext_vector_type(2)));
typedef _Float16 h8   __attribute__((ext_vector_type(8)));
typedef float    f32x4 __attribute__((ext_vector_type(4)));

__device__ __forceinline__ uint32 pkrtz(float a, float b) {
    h2b r = __builtin_amdgcn_cvt_pkrtz(a, b);
    return __builtin_bit_cast(uint32, r);
}
__device__ __forceinline__ float dot2(uint32 a, uint32 b, float c) {
#if __has_builtin(__builtin_amdgcn_fdot2)
    return __builtin_amdgcn_fdot2(__builtin_bit_cast(h2b, a),
                                  __builtin_bit_cast(h2b, b), c, false);
#else
    h2 x = __builtin_bit_cast(h2, a), y = __builtin_bit_cast(h2, b);
    return c + (float)x.x * (float)y.x + (float)x.y * (float)y.y;
#endif
}
__device__ __forceinline__ float dot16(uint4 q, uint4 r, float s) {
    s = dot2(q.x, r.x, s); s = dot2(q.y, r.y, s);
    s = dot2(q.z, r.z, s); s = dot2(q.w, r.w, s);
    return s;
}
__device__ __forceinline__ f32x4 mfma16(uint4 a, uint4 b, f32x4 c) {
    return __builtin_amdgcn_mfma_f32_16x16x32_f16(
        __builtin_bit_cast(h8, a), __builtin_bit_cast(h8, b), c, 0, 0, 0);
}
__device__ __forceinline__ uint4 pack_w8(const float* __restrict__ w) {
    const float4 lo = *(const float4*)w;
    const float4 hi = *(const float4*)(w + 4);
    uint4 r;
    r.x = pkrtz(lo.x, lo.y); r.y = pkrtz(lo.z, lo.w);
    r.z = pkrtz(hi.x, hi.y); r.w = pkrtz(hi.z, hi.w);
    return r;
}

// ---------------------------------------------------------------------------
// Fused local attention, 16x16 tiles, 256 blocks x 1024 threads (R1 geometry,
// best measured). New in this round: score+agg phases restructured from
// thread-quads (1 px, 4 lanes x 16ch) to 8-lane groups (2 adjacent px,
// 8 lanes x 8ch) sharing the 5x6 union of the two 5x5 stencils:
// LDS reads in score+agg drop 40% (819 KB -> 491 KB each), conflict-free
// (8 groups/wave hit 8 distinct SWZ rows). Reduce is 3-level shfl_xor.
//   P0: stage y->A, x->B.                 barrier[1]
//   P1: q-conv(A) + v-conv(B) + xres(B).  barrier[2]
//   P2: q->A, v->B.                       barrier[3]
//   P3: scores(A, pairs) + softmax x2 + agg(B, pairs).   barrier[4]
//   P4: agg->A rows 0..255.               barrier[5]
//   P5: final conv(A) + residual + store (full 64B lines).
// ---------------------------------------------------------------------------
__global__ __launch_bounds__(1024, 4)
void fused_attn(const float* __restrict__ x, const float* __restrict__ y,
                const float* __restrict__ wx, const float* __restrict__ bx,
                const float* __restrict__ wy, const float* __restrict__ by,
                const float* __restrict__ wo, const float* __restrict__ bo,
                float* __restrict__ out)
{
    __shared__ uint32 Ah[NHP * 32];   // 50 KiB
    __shared__ uint32 Bh[NHP * 32];   // 50 KiB

    // ---- XCD-aware tile mapping ----
    const int lin  = blockIdx.x;          // 0..255
    const int xcd  = lin & 7;
    const int rr   = lin >> 3;            // 0..31 within XCD
    const int b    = xcd >> 1;            // 2 XCDs per batch
    const int half = xcd & 1;             // top/bottom 4 tile-rows
    const int ty0  = ((rr >> 3) + half * 4) * TILE;
    const int tx0  = (rr & 7) * TILE;

    const int t = threadIdx.x;

    // ---- P0: stage y->A, x->B as f16, pixel-PAIR float2 loads, swizzled ----
    for (int i = t; i < NHP * 8 / 2; i += 1024) {      // 1600 pair-items
        const int c   = i / 200;                       // channel octet 0..7
        const int rem = i - c * 200;
        const int hy  = rem / 10;
        const int hx  = (rem - hy * 10) * 2;           // even column
        const int pix = hy * HALO + hx;
        int gy = ty0 + hy - 2, gx = tx0 + hx - 2;      // gx even
        const bool ok = ((unsigned)gy < HH) & ((unsigned)gx < (WW - 1));
        if (!ok) { gy = 0; gx = 0; }     // clamp; conv out zeroed at write
        const size_t base = (size_t)b * CC * HW + (size_t)(c * 8) * HW
                          + (size_t)gy * WW + gx;
        float2 yv[8], xv[8];
        #pragma unroll
        for (int j = 0; j < 8; ++j) {
            yv[j] = *(const float2*)(y + base + (size_t)j * HW);
            xv[j] = *(const float2*)(x + base + (size_t)j * HW);
        }
        uint4 q0, q1;
        q0.x = pkrtz(yv[0].x, yv[1].x); q0.y = pkrtz(yv[2].x, yv[3].x);
        q0.z = pkrtz(yv[4].x, yv[5].x); q0.w = pkrtz(yv[6].x, yv[7].x);
        q1.x = pkrtz(yv[0].y, yv[1].y); q1.y = pkrtz(yv[2].y, yv[3].y);
        q1.z = pkrtz(yv[4].y, yv[5].y); q1.w = pkrtz(yv[6].y, yv[7].y);
        *(uint4*)&Ah[pix * 32 + (c ^ SWZ(pix)) * 4]           = q0;
        *(uint4*)&Ah[(pix + 1) * 32 + (c ^ SWZ(pix + 1)) * 4] = q1;
        q0.x = pkrtz(xv[0].x, xv[1].x); q0.y = pkrtz(xv[2].x, xv[3].x);
        q0.z = pkrtz(xv[4].x, xv[5].x); q0.w = pkrtz(xv[6].x, xv[7].x);
        q1.x = pkrtz(xv[0].y, xv[1].y); q1.y = pkrtz(xv[2].y, xv[3].y);
        q1.z = pkrtz(xv[4].y, xv[5].y); q1.w = pkrtz(xv[6].y, xv[7].y);
        *(uint4*)&Bh[pix * 32 + (c ^ SWZ(pix)) * 4]           = q0;
        *(uint4*)&Bh[(pix + 1) * 32 + (c ^ SWZ(pix + 1)) * 4] = q1;
    }
    __syncthreads();                                   // [1]

    const int wv = t >> 6;        // wave id 0..15
    const int ln = t & 63;
    const int lm = ln & 15;
    const int qd = ln >> 4;
    const int ot = wv & 3;        // this wave's 16-oc tile

    // ---- P1: q-conv + v-conv (interleaved MFMA) + residual slice save ----
    f32x4 accq[7], accv[7];
    uint2 xres[4];
    {
        const uint4 aq0 = pack_w8(wy + (ot * 16 + lm) * CC + qd * 8);
        const uint4 aq1 = pack_w8(wy + (ot * 16 + lm) * CC + qd * 8 + 32);
        const uint4 av0 = pack_w8(wx + (ot * 16 + lm) * CC + qd * 8);
        const uint4 av1 = pack_w8(wx + (ot * 16 + lm) * CC + qd * 8 + 32);
        #pragma unroll
        for (int k = 0; k < 7; ++k) {
            const int j = wv + k * 16;
            if (j < 100) {
                const int px = (j >> 2) * 16 + lm, sw = SWZ(px);
                const uint4 b0 = *(const uint4*)&Ah[px * 32 + ((qd    ) ^ sw) * 4];
                const uint4 b1 = *(const uint4*)&Ah[px * 32 + ((qd + 4) ^ sw) * 4];
                f32x4 a = {0.f, 0.f, 0.f, 0.f};
                a = mfma16(aq0, b0, a); a = mfma16(aq1, b1, a); accq[k] = a;
                const uint4 c0 = *(const uint4*)&Bh[px * 32 + ((qd    ) ^ sw) * 4];
                const uint4 c1 = *(const uint4*)&Bh[px * 32 + ((qd + 4) ^ sw) * 4];
                f32x4 v = {0.f, 0.f, 0.f, 0.f};
                v = mfma16(av0, c0, v); v = mfma16(av1, c1, v); accv[k] = v;
            }
        }
        #pragma unroll
        for (int k = 0; k < 4; ++k) {   // f16 x at this lane's final out px/chs
            const int px = ((wv >> 2) + k * 4) * 16 + lm;        // 0..255
            const int hpix = ((px >> 4) + 2) * HALO + (px & 15) + 2;
            const int chunk = ot * 2 + (qd >> 1);
            xres[k] = *(const uint2*)
                &Bh[hpix * 32 + (chunk ^ SWZ(hpix)) * 4 + (qd & 1) * 2];
        }
    }
    __syncthreads();                                   // [2] halo reads done

    // ---- P2: write q->A, v->B (OOB => 0: zero-pad is AFTER conv+bias) ----
    {
        const float4 bq = *(const float4*)(by + ot * 16 + qd * 4);
        const float4 bv = *(const float4*)(bx + ot * 16 + qd * 4);
        const int chunk = ot * 2 + (qd >> 1);
        #pragma unroll
        for (int k = 0; k < 7; ++k) {
            const int j = wv + k * 16;
            if (j < 100) {
                const int px = (j >> 2) * 16 + lm;
                const int hy = px / HALO, hx = px - hy * HALO;
                const int gy = ty0 + hy - 2, gx = tx0 + hx - 2;
                uint2 wq = {0u, 0u}, wvv = {0u, 0u};
                if (((unsigned)gy < HH) & ((unsigned)gx < WW)) {
                    wq.x  = pkrtz(accq[k].x + bq.x, accq[k].y + bq.y);
                    wq.y  = pkrtz(accq[k].z + bq.z, accq[k].w + bq.w);
                    wvv.x = pkrtz(accv[k].x + bv.x, accv[k].y + bv.y);
                    wvv.y = pkrtz(accv[k].z + bv.z, accv[k].w + bv.w);
                }
                const int off = px * 32 + (chunk ^ SWZ(px)) * 4 + (qd & 1) * 2;
                *(uint2*)&Ah[off] = wq;
                *(uint2*)&Bh[off] = wvv;
            }
        }
    }
    __syncthreads();                                   // [3] q,v visible

    // ---- P3: scores from A — PIXEL-PAIR groups: 8 lanes x 8 ch, 2 px ----
    const int g   = t >> 3, sub = t & 7;               // pair 0..127, octet 0..7
    const int py  = g >> 3, pc2 = (g & 7) * 2;         // pa col even
    const int crA = (py + 2) * HALO + (pc2 + 2);
    const int crB = crA + 1;

    const uint4 qa = *(const uint4*)&Ah[crA * 32 + (sub ^ SWZ(crA)) * 4];
    const uint4 qb = *(const uint4*)&Ah[crB * 32 + (sub ^ SWZ(crB)) * 4];

    float sa[25], sb[25];
    #pragma unroll
    for (int k = 0; k < 25; ++k) { sa[k] = 0.f; sb[k] = 0.f; }
    #pragma unroll
    for (int dy = 0; dy < 5; ++dy)
        #pragma unroll
        for (int du = 0; du < 6; ++du) {   // union of the two 5x5 stencils
            const int nrow = (py + dy) * HALO + (pc2 + du);
            const uint4 r = *(const uint4*)&Ah[nrow * 32 + (sub ^ SWZ(nrow)) * 4];
            if (du < 5) sa[dy * 5 + du]     = dot16(qa, r, sa[dy * 5 + du]);
            if (du > 0) sb[dy * 5 + du - 1] = dot16(qb, r, sb[dy * 5 + du - 1]);
        }
    // 8-lane reduce (each lane had an 8-ch partial)
    #pragma unroll
    for (int k = 0; k < 25; ++k) {
        float v = sa[k];
        v += __shfl_xor(v, 1); v += __shfl_xor(v, 2); v += __shfl_xor(v, 4);
        sa[k] = v;
        float w = sb[k];
        w += __shfl_xor(w, 1); w += __shfl_xor(w, 2); w += __shfl_xor(w, 4);
        sb[k] = w;
    }

    // softmax over 25, both pixels (duplicated across the 8 lanes)
    {
        float mxa = sa[24], mxb = sb[24];
        #pragma unroll
        for (int k = 0; k < 24; k += 2) {
            mxa = fmaxf(mxa, fmaxf(sa[k], sa[k + 1]));
            mxb = fmaxf(mxb, fmaxf(sb[k], sb[k + 1]));
        }
        float suma = 0.f, sumb = 0.f;
        #pragma unroll
        for (int k = 0; k < 25; ++k) {
            sa[k] = __expf(sa[k] - mxa); suma += sa[k];
            sb[k] = __expf(sb[k] - mxb); sumb += sb[k];
        }
        const float iva = 1.f / suma, ivb = 1.f / sumb;
        #pragma unroll
        for (int k = 0; k < 25; ++k) { sa[k] *= iva; sb[k] *= ivb; }
    }

    // ---- aggregate v from B — same pair structure ----
    h2 aga[4], agb[4];
    #pragma unroll
    for (int k = 0; k < 4; ++k) { aga[k] = (h2)(_Float16)0; agb[k] = (h2)(_Float16)0; }
    #pragma unroll
    for (int dy = 0; dy < 5; ++dy)
        #pragma unroll
        for (int du = 0; du < 6; ++du) {
            const int nrow = (py + dy) * HALO + (pc2 + du);
            const uint4 r = *(const uint4*)&Bh[nrow * 32 + (sub ^ SWZ(nrow)) * 4];
            if (du < 5) {
                const _Float16 af = (_Float16)sa[dy * 5 + du];
                const h2 a2 = {af, af};
                aga[0] += a2 * __builtin_bit_cast(h2, r.x);
                aga[1] += a2 * __builtin_bit_cast(h2, r.y);
                aga[2] += a2 * __builtin_bit_cast(h2, r.z);
                aga[3] += a2 * __builtin_bit_cast(h2, r.w);
            }
            if (du > 0) {
                const _Float16 bf = (_Float16)sb[dy * 5 + du - 1];
                const h2 b2 = {bf, bf};
                agb[0] += b2 * __builtin_bit_cast(h2, r.x);
                agb[1] += b2 * __builtin_bit_cast(h2, r.y);
                agb[2] += b2 * __builtin_bit_cast(h2, r.z);
                agb[3] += b2 * __builtin_bit_cast(h2, r.w);
            }
        }

    __syncthreads();                                   // [4] A,B reads done

    // ---- P4: agg -> A rows 0..255 (same chunk semantics as staging) ----
    {
        const int pa = py * 16 + pc2, pb = pa + 1;
        uint4 wa, wb;
        wa.x = __builtin_bit_cast(uint32, aga[0]); wa.y = __builtin_bit_cast(uint32, aga[1]);
        wa.z = __builtin_bit_cast(uint32, aga[2]); wa.w = __builtin_bit_cast(uint32, aga[3]);
        wb.x = __builtin_bit_cast(uint32, agb[0]); wb.y = __builtin_bit_cast(uint32, agb[1]);
        wb.z = __builtin_bit_cast(uint32, agb[2]); wb.w = __builtin_bit_cast(uint32, agb[3]);
        *(uint4*)&Ah[pa * 32 + (sub ^ SWZ(pa)) * 4] = wa;
        *(uint4*)&Ah[pb * 32 + (sub ^ SWZ(pb)) * 4] = wb;
    }
    __syncthreads();                                   // [5]

    // ---- P5: final conv (MFMA) + bias + f16 residual from regs ----
    {
        const uint4 a0 = pack_w8(wo + (ot * 16 + lm) * CC + qd * 8);
        const uint4 a1 = pack_w8(wo + (ot * 16 + lm) * CC + qd * 8 + 32);
        const float4 bq = *(const float4*)(bo + ot * 16 + qd * 4);
        #pragma unroll
        for (int k = 0; k < 4; ++k) {
            const int px = ((wv >> 2) + k * 4) * 16 + lm, sw = SWZ(px);
            const uint4 b0 = *(const uint4*)&Ah[px * 32 + ((qd    ) ^ sw) * 4];
            const uint4 b1 = *(const uint4*)&Ah[px * 32 + ((qd + 4) ^ sw) * 4];
            f32x4 a = {0.f, 0.f, 0.f, 0.f};
            a = mfma16(a0, b0, a);
            a = mfma16(a1, b1, a);
            const int gh = ty0 + (px >> 4), gw = tx0 + (px & 15);
            const h2 xp0 = __builtin_bit_cast(h2, xres[k].x);  // ch qd*4+0,1
            const h2 xp1 = __builtin_bit_cast(h2, xres[k].y);  // ch qd*4+2,3
            const float rv[4] = {(float)xp0.x, (float)xp0.y,
                                 (float)xp1.x, (float)xp1.y};
            const float av4[4] = {a.x + bq.x, a.y + bq.y, a.z + bq.z, a.w + bq.w};
            #pragma unroll
            for (int r = 0; r < 4; ++r) {
                const int oc = ot * 16 + qd * 4 + r;
                const size_t ad = (size_t)(b * CC + oc) * HW + (size_t)gh * WW + gw;
                out[ad] = av4[r] + rv[r];   // 16 lanes -> one full 64B line
            }
        }
    }
}

// ---------------------------------------------------------------------------
extern "C" void kernel_launch(void* const* d_in, const int* in_sizes, int n_in,
                              void* d_out, int out_size, void* d_ws, size_t ws_size,
                              hipStream_t stream) {
    const float* x  = (const float*)d_in[0];
    const float* y  = (const float*)d_in[1];
    const float* wx = (const float*)d_in[2];
    const float* bx = (const float*)d_in[3];
    const float* wy = (const float*)d_in[4];
    const float* by = (const float*)d_in[5];
    const float* wo = (const float*)d_in[6];
    const float* bo = (const float*)d_in[7];
    float* out = (float*)d_out;
    (void)d_ws; (void)ws_size;

    fused_attn<<<dim3(256), 1024, 0, stream>>>(x, y, wx, bx, wy, by, wo, bo, out);
}

// Round 5
// 114.078 us; speedup vs baseline: 1.1072x; 1.1072x over previous
//
#include <hip/hip_runtime.h>

#define HH   128
#define WW   128
#define HW   (HH * WW)
#define CC   64
#define TILE 16
#define HALO 20
#define NHP  (HALO * HALO)   // 400 halo pixels = 25 exact 16-px MFMA tiles
#define SWZ(r) (((r) >> 1) & 7)

typedef unsigned int uint32;
typedef _Float16 h2   __attribute__((ext_vector_type(2)));
typedef __fp16   h2b  __attribute__((ext_vector_type(2)));
typedef _Float16 h8   __attribute__((ext_vector_type(8)));
typedef float    f32x4 __attribute__((ext_vector_type(4)));

__device__ __forceinline__ uint32 pkrtz(float a, float b) {
    h2b r = __builtin_amdgcn_cvt_pkrtz(a, b);
    return __builtin_bit_cast(uint32, r);
}
__device__ __forceinline__ float dot2(uint32 a, uint32 b, float c) {
#if __has_builtin(__builtin_amdgcn_fdot2)
    return __builtin_amdgcn_fdot2(__builtin_bit_cast(h2b, a),
                                  __builtin_bit_cast(h2b, b), c, false);
#else
    h2 x = __builtin_bit_cast(h2, a), y = __builtin_bit_cast(h2, b);
    return c + (float)x.x * (float)y.x + (float)x.y * (float)y.y;
#endif
}
__device__ __forceinline__ f32x4 mfma16(uint4 a, uint4 b, f32x4 c) {
    return __builtin_amdgcn_mfma_f32_16x16x32_f16(
        __builtin_bit_cast(h8, a), __builtin_bit_cast(h8, b), c, 0, 0, 0);
}
__device__ __forceinline__ uint4 pack_w8(const float* __restrict__ w) {
    const float4 lo = *(const float4*)w;
    const float4 hi = *(const float4*)(w + 4);
    uint4 r;
    r.x = pkrtz(lo.x, lo.y); r.y = pkrtz(lo.z, lo.w);
    r.z = pkrtz(hi.x, hi.y); r.w = pkrtz(hi.z, hi.w);
    return r;
}

// ---------------------------------------------------------------------------
// Fused local attention, 16x16 tiles, 256 blocks x 1024 threads (R1 geometry,
// best measured). R5 changes vs R1:
//  (a) staging re-partitioned: 800 items of 2px x 16ch -> every thread does
//      at most ONE item (R1: 576 threads did two -> staging makespan 2x).
//      y-half then x-half sequentially: <=40 live VGPRs (the R4 post-mortem
//      showed the allocator caps at 64 and anything above goes to scratch:
//      WRITE_SIZE 99 MB vs 17 MB ideal).
//  (b) amdgpu_waves_per_eu(4,4): exactly 4 waves/EU (16-wave block, 1
//      block/CU by LDS) -> allocator may use up to 128 VGPRs, no forced
//      remat/micro-spill.
//   P0: stage y->A, x->B.                 barrier[1]
//   P1: q-conv(A) + v-conv(B) + xres(B).  barrier[2]
//   P2: q->A, v->B.                       barrier[3]
//   P3: scores(A, quads) + softmax + agg(B).   barrier[4]
//   P4: agg->A rows 0..255.               barrier[5]
//   P5: final conv(A) + residual + store (full 64B lines).
// ---------------------------------------------------------------------------
__global__ __attribute__((amdgpu_flat_work_group_size(1024, 1024),
                          amdgpu_waves_per_eu(4, 4)))
void fused_attn(const float* __restrict__ x, const float* __restrict__ y,
                const float* __restrict__ wx, const float* __restrict__ bx,
                const float* __restrict__ wy, const float* __restrict__ by,
                const float* __restrict__ wo, const float* __restrict__ bo,
                float* __restrict__ out)
{
    __shared__ uint32 Ah[NHP * 32];   // 50 KiB
    __shared__ uint32 Bh[NHP * 32];   // 50 KiB

    // ---- XCD-aware tile mapping ----
    const int lin  = blockIdx.x;          // 0..255
    const int xcd  = lin & 7;
    const int rr   = lin >> 3;            // 0..31 within XCD
    const int b    = xcd >> 1;            // 2 XCDs per batch
    const int half = xcd & 1;             // top/bottom 4 tile-rows
    const int ty0  = ((rr >> 3) + half * 4) * TILE;
    const int tx0  = (rr & 7) * TILE;

    const int t = threadIdx.x;

    // ---- P0: stage y->A then x->B; 800 items = 200 pixel-pairs x 4 ch-groups;
    //      one item per thread (threads 800..1023 idle this phase) ----
    if (t < 800) {
        const int cg  = t / 200;                       // 16-ch group 0..3
        const int rem = t - cg * 200;                  // pixel pair 0..199
        const int hy  = rem / 10;
        const int hx  = (rem - hy * 10) * 2;           // even column
        const int pix = hy * HALO + hx;
        int gy = ty0 + hy - 2, gx = tx0 + hx - 2;      // gx even
        const bool ok = ((unsigned)gy < HH) & ((unsigned)gx < (WW - 1));
        if (!ok) { gy = 0; gx = 0; }     // clamp; conv out zeroed at write
        const size_t base = (size_t)b * CC * HW + (size_t)(cg * 16) * HW
                          + (size_t)gy * WW + gx;
        const int w0 = ((cg * 2    ) ^ SWZ(pix)) * 4;
        const int w1 = ((cg * 2 + 1) ^ SWZ(pix)) * 4;
        const int w2 = ((cg * 2    ) ^ SWZ(pix + 1)) * 4;
        const int w3 = ((cg * 2 + 1) ^ SWZ(pix + 1)) * 4;
        {   // y half (16 float2 in flight, ~36 live regs)
            float2 v[16];
            #pragma unroll
            for (int j = 0; j < 16; ++j)
                v[j] = *(const float2*)(y + base + (size_t)j * HW);
            uint4 q0, q1, q2, q3;
            q0.x = pkrtz(v[0].x,  v[1].x);  q0.y = pkrtz(v[2].x,  v[3].x);
            q0.z = pkrtz(v[4].x,  v[5].x);  q0.w = pkrtz(v[6].x,  v[7].x);
            q1.x = pkrtz(v[8].x,  v[9].x);  q1.y = pkrtz(v[10].x, v[11].x);
            q1.z = pkrtz(v[12].x, v[13].x); q1.w = pkrtz(v[14].x, v[15].x);
            q2.x = pkrtz(v[0].y,  v[1].y);  q2.y = pkrtz(v[2].y,  v[3].y);
            q2.z = pkrtz(v[4].y,  v[5].y);  q2.w = pkrtz(v[6].y,  v[7].y);
            q3.x = pkrtz(v[8].y,  v[9].y);  q3.y = pkrtz(v[10].y, v[11].y);
            q3.z = pkrtz(v[12].y, v[13].y); q3.w = pkrtz(v[14].y, v[15].y);
            *(uint4*)&Ah[pix * 32 + w0]       = q0;
            *(uint4*)&Ah[pix * 32 + w1]       = q1;
            *(uint4*)&Ah[(pix + 1) * 32 + w2] = q2;
            *(uint4*)&Ah[(pix + 1) * 32 + w3] = q3;
        }
        {   // x half
            float2 v[16];
            #pragma unroll
            for (int j = 0; j < 16; ++j)
                v[j] = *(const float2*)(x + base + (size_t)j * HW);
            uint4 q0, q1, q2, q3;
            q0.x = pkrtz(v[0].x,  v[1].x);  q0.y = pkrtz(v[2].x,  v[3].x);
            q0.z = pkrtz(v[4].x,  v[5].x);  q0.w = pkrtz(v[6].x,  v[7].x);
            q1.x = pkrtz(v[8].x,  v[9].x);  q1.y = pkrtz(v[10].x, v[11].x);
            q1.z = pkrtz(v[12].x, v[13].x); q1.w = pkrtz(v[14].x, v[15].x);
            q2.x = pkrtz(v[0].y,  v[1].y);  q2.y = pkrtz(v[2].y,  v[3].y);
            q2.z = pkrtz(v[4].y,  v[5].y);  q2.w = pkrtz(v[6].y,  v[7].y);
            q3.x = pkrtz(v[8].y,  v[9].y);  q3.y = pkrtz(v[10].y, v[11].y);
            q3.z = pkrtz(v[12].y, v[13].y); q3.w = pkrtz(v[14].y, v[15].y);
            *(uint4*)&Bh[pix * 32 + w0]       = q0;
            *(uint4*)&Bh[pix * 32 + w1]       = q1;
            *(uint4*)&Bh[(pix + 1) * 32 + w2] = q2;
            *(uint4*)&Bh[(pix + 1) * 32 + w3] = q3;
        }
    }
    __syncthreads();                                   // [1]

    const int wv = t >> 6;        // wave id 0..15
    const int ln = t & 63;
    const int lm = ln & 15;
    const int qd = ln >> 4;
    const int ot = wv & 3;        // this wave's 16-oc tile

    // ---- P1: q-conv + v-conv (interleaved MFMA) + residual slice save ----
    f32x4 accq[7], accv[7];
    uint2 xres[4];
    {
        const uint4 aq0 = pack_w8(wy + (ot * 16 + lm) * CC + qd * 8);
        const uint4 aq1 = pack_w8(wy + (ot * 16 + lm) * CC + qd * 8 + 32);
        const uint4 av0 = pack_w8(wx + (ot * 16 + lm) * CC + qd * 8);
        const uint4 av1 = pack_w8(wx + (ot * 16 + lm) * CC + qd * 8 + 32);
        #pragma unroll
        for (int k = 0; k < 7; ++k) {
            const int j = wv + k * 16;
            if (j < 100) {
                const int px = (j >> 2) * 16 + lm, sw = SWZ(px);
                const uint4 b0 = *(const uint4*)&Ah[px * 32 + ((qd    ) ^ sw) * 4];
                const uint4 b1 = *(const uint4*)&Ah[px * 32 + ((qd + 4) ^ sw) * 4];
                f32x4 a = {0.f, 0.f, 0.f, 0.f};
                a = mfma16(aq0, b0, a); a = mfma16(aq1, b1, a); accq[k] = a;
                const uint4 c0 = *(const uint4*)&Bh[px * 32 + ((qd    ) ^ sw) * 4];
                const uint4 c1 = *(const uint4*)&Bh[px * 32 + ((qd + 4) ^ sw) * 4];
                f32x4 v = {0.f, 0.f, 0.f, 0.f};
                v = mfma16(av0, c0, v); v = mfma16(av1, c1, v); accv[k] = v;
            }
        }
        #pragma unroll
        for (int k = 0; k < 4; ++k) {   // f16 x at this lane's final out px/chs
            const int px = ((wv >> 2) + k * 4) * 16 + lm;        // 0..255
            const int hpix = ((px >> 4) + 2) * HALO + (px & 15) + 2;
            const int chunk = ot * 2 + (qd >> 1);
            xres[k] = *(const uint2*)
                &Bh[hpix * 32 + (chunk ^ SWZ(hpix)) * 4 + (qd & 1) * 2];
        }
    }
    __syncthreads();                                   // [2] halo reads done

    // ---- P2: write q->A, v->B (OOB => 0: zero-pad is AFTER conv+bias) ----
    {
        const float4 bq = *(const float4*)(by + ot * 16 + qd * 4);
        const float4 bv = *(const float4*)(bx + ot * 16 + qd * 4);
        const int chunk = ot * 2 + (qd >> 1);
        #pragma unroll
        for (int k = 0; k < 7; ++k) {
            const int j = wv + k * 16;
            if (j < 100) {
                const int px = (j >> 2) * 16 + lm;
                const int hy = px / HALO, hx = px - hy * HALO;
                const int gy = ty0 + hy - 2, gx = tx0 + hx - 2;
                uint2 wq = {0u, 0u}, wvv = {0u, 0u};
                if (((unsigned)gy < HH) & ((unsigned)gx < WW)) {
                    wq.x  = pkrtz(accq[k].x + bq.x, accq[k].y + bq.y);
                    wq.y  = pkrtz(accq[k].z + bq.z, accq[k].w + bq.w);
                    wvv.x = pkrtz(accv[k].x + bv.x, accv[k].y + bv.y);
                    wvv.y = pkrtz(accv[k].z + bv.z, accv[k].w + bv.w);
                }
                const int off = px * 32 + (chunk ^ SWZ(px)) * 4 + (qd & 1) * 2;
                *(uint2*)&Ah[off] = wq;
                *(uint2*)&Bh[off] = wvv;
            }
        }
    }
    __syncthreads();                                   // [3] q,v visible

    // ---- P3: scores (from A): 1 pixel per thread-quad, 16 ch per sub-lane ----
    const int p    = t >> 2, sub = t & 3;              // p 0..255
    const int py   = p >> 4, pxl = p & 15;
    const int crow = (py + 2) * HALO + (pxl + 2);

    uint32 qc[8];
    {
        const int c0 = ((2 * sub)     ^ SWZ(crow)) * 4;
        const int c1 = ((2 * sub + 1) ^ SWZ(crow)) * 4;
        *(uint4*)&qc[0] = *(const uint4*)&Ah[crow * 32 + c0];
        *(uint4*)&qc[4] = *(const uint4*)&Ah[crow * 32 + c1];
    }

    float sc[25];
    #pragma unroll
    for (int dy = 0; dy < 5; ++dy)
        #pragma unroll
        for (int dx = 0; dx < 5; ++dx) {
            const int nrow = (py + dy) * HALO + (pxl + dx);
            const int c0 = ((2 * sub)     ^ SWZ(nrow)) * 4;
            const int c1 = ((2 * sub + 1) ^ SWZ(nrow)) * 4;
            const uint4 r0 = *(const uint4*)&Ah[nrow * 32 + c0];
            const uint4 r1 = *(const uint4*)&Ah[nrow * 32 + c1];
            float s = 0.f;
            s = dot2(qc[0], r0.x, s); s = dot2(qc[1], r0.y, s);
            s = dot2(qc[2], r0.z, s); s = dot2(qc[3], r0.w, s);
            s = dot2(qc[4], r1.x, s); s = dot2(qc[5], r1.y, s);
            s = dot2(qc[6], r1.z, s); s = dot2(qc[7], r1.w, s);
            s += __shfl_xor(s, 1);
            s += __shfl_xor(s, 2);      // identical across the 4 sub-lanes
            sc[dy * 5 + dx] = s;
        }

    // softmax over 25 — pairwise trees (v_max3 fusion, depth 24 -> 12)
    float mx = sc[24];
    #pragma unroll
    for (int k = 0; k < 24; k += 2) mx = fmaxf(mx, fmaxf(sc[k], sc[k + 1]));
    #pragma unroll
    for (int k = 0; k < 25; ++k) sc[k] = __expf(sc[k] - mx);
    float sum = sc[24];
    #pragma unroll
    for (int k = 0; k < 24; k += 2) sum += sc[k] + sc[k + 1];
    const float inv = 1.f / sum;

    // ---- aggregate v (from B, packed f16 fma) ----
    h2 ag[8];
    #pragma unroll
    for (int k = 0; k < 8; ++k) ag[k] = (h2)(_Float16)0;
    #pragma unroll
    for (int dy = 0; dy < 5; ++dy)
        #pragma unroll
        for (int dx = 0; dx < 5; ++dx) {
            const int nrow = (py + dy) * HALO + (pxl + dx);
            const int c0 = ((2 * sub)     ^ SWZ(nrow)) * 4;
            const int c1 = ((2 * sub + 1) ^ SWZ(nrow)) * 4;
            const uint4 r0 = *(const uint4*)&Bh[nrow * 32 + c0];
            const uint4 r1 = *(const uint4*)&Bh[nrow * 32 + c1];
            const _Float16 af = (_Float16)(sc[dy * 5 + dx] * inv);
            const h2 a2 = {af, af};
            ag[0] += a2 * __builtin_bit_cast(h2, r0.x);
            ag[1] += a2 * __builtin_bit_cast(h2, r0.y);
            ag[2] += a2 * __builtin_bit_cast(h2, r0.z);
            ag[3] += a2 * __builtin_bit_cast(h2, r0.w);
            ag[4] += a2 * __builtin_bit_cast(h2, r1.x);
            ag[5] += a2 * __builtin_bit_cast(h2, r1.y);
            ag[6] += a2 * __builtin_bit_cast(h2, r1.z);
            ag[7] += a2 * __builtin_bit_cast(h2, r1.w);
        }

    __syncthreads();                                   // [4] A,B reads done

    // ---- P4: agg -> A rows 0..255 (same swizzled layout) ----
    {
        const int c0 = ((2 * sub)     ^ SWZ(p)) * 4;
        const int c1 = ((2 * sub + 1) ^ SWZ(p)) * 4;
        uint4 w0, w1;
        w0.x = __builtin_bit_cast(uint32, ag[0]); w0.y = __builtin_bit_cast(uint32, ag[1]);
        w0.z = __builtin_bit_cast(uint32, ag[2]); w0.w = __builtin_bit_cast(uint32, ag[3]);
        w1.x = __builtin_bit_cast(uint32, ag[4]); w1.y = __builtin_bit_cast(uint32, ag[5]);
        w1.z = __builtin_bit_cast(uint32, ag[6]); w1.w = __builtin_bit_cast(uint32, ag[7]);
        *(uint4*)&Ah[p * 32 + c0] = w0;
        *(uint4*)&Ah[p * 32 + c1] = w1;
    }
    __syncthreads();                                   // [5]

    // ---- P5: final conv (MFMA) + bias + f16 residual from regs ----
    {
        const uint4 a0 = pack_w8(wo + (ot * 16 + lm) * CC + qd * 8);
        const uint4 a1 = pack_w8(wo + (ot * 16 + lm) * CC + qd * 8 + 32);
        const float4 bq = *(const float4*)(bo + ot * 16 + qd * 4);
        #pragma unroll
        for (int k = 0; k < 4; ++k) {
            const int px = ((wv >> 2) + k * 4) * 16 + lm, sw = SWZ(px);
            const uint4 b0 = *(const uint4*)&Ah[px * 32 + ((qd    ) ^ sw) * 4];
            const uint4 b1 = *(const uint4*)&Ah[px * 32 + ((qd + 4) ^ sw) * 4];
            f32x4 a = {0.f, 0.f, 0.f, 0.f};
            a = mfma16(a0, b0, a);
            a = mfma16(a1, b1, a);
            const int gh = ty0 + (px >> 4), gw = tx0 + (px & 15);
            const h2 xp0 = __builtin_bit_cast(h2, xres[k].x);  // ch qd*4+0,1
            const h2 xp1 = __builtin_bit_cast(h2, xres[k].y);  // ch qd*4+2,3
            const float rv[4] = {(float)xp0.x, (float)xp0.y,
                                 (float)xp1.x, (float)xp1.y};
            const float av4[4] = {a.x + bq.x, a.y + bq.y, a.z + bq.z, a.w + bq.w};
            #pragma unroll
            for (int r = 0; r < 4; ++r) {
                const int oc = ot * 16 + qd * 4 + r;
                const size_t ad = (size_t)(b * CC + oc) * HW + (size_t)gh * WW + gw;
                out[ad] = av4[r] + rv[r];   // 16 lanes -> one full 64B line
            }
        }
    }
}

// ---------------------------------------------------------------------------
extern "C" void kernel_launch(void* const* d_in, const int* in_sizes, int n_in,
                              void* d_out, int out_size, void* d_ws, size_t ws_size,
                              hipStream_t stream) {
    const float* x  = (const float*)d_in[0];
    const float* y  = (const float*)d_in[1];
    const float* wx = (const float*)d_in[2];
    const float* bx = (const float*)d_in[3];
    const float* wy = (const float*)d_in[4];
    const float* by = (const float*)d_in[5];
    const float* wo = (const float*)d_in[6];
    const float* bo = (const float*)d_in[7];
    float* out = (float*)d_out;
    (void)d_ws; (void)ws_size;

    fused_attn<<<dim3(256), 1024, 0, stream>>>(x, y, wx, bx, wy, by, wo, bo, out);
}